// Round 16
// baseline (203.413 us; speedup 1.0000x reference)
//
#include <hip/hip_runtime.h>

typedef _Float16 half4 __attribute__((ext_vector_type(4)));
typedef _Float16 half8 __attribute__((ext_vector_type(8)));

// ---------------- graph preprocessing (deterministic bucketed sort) ----------------
// Buckets of 64 consecutive dst nodes; chunks of 4096 edges.
// hist[chunk][bucket] -> per-bucket scan across chunks -> deterministic scatter.
// part[] entries packed as (src << 6) | (dst & 63).

static constexpr int NPB_SHIFT = 6;           // 64 nodes per bucket
static constexpr int NPB = 1 << NPB_SHIFT;
static constexpr int MAX_BKT = 1024;          // supports n <= 65536 (src<<6 fits int)
static constexpr int PS_CHUNK = 4096;         // edges per chunk

// K1: per-chunk bucket histogram (LDS atomics only)
__global__ __launch_bounds__(256) void hist_kernel(const int* __restrict__ dst, int E,
                                                   int nbkt, int* __restrict__ hist) {
    __shared__ int lc[MAX_BKT];
    int tid = threadIdx.x;
    int b = blockIdx.x;
    int e0 = b * PS_CHUNK;
    int e1 = e0 + PS_CHUNK; if (e1 > E) e1 = E;
    for (int i = tid; i < nbkt; i += 256) lc[i] = 0;
    __syncthreads();
    for (int i = e0 + tid; i < e1; i += 256)
        atomicAdd(&lc[dst[i] >> NPB_SHIFT], 1);
    __syncthreads();
    for (int i = tid; i < nbkt; i += 256) hist[(size_t)b * nbkt + i] = lc[i];
}

// K2a: per-bucket exclusive scan across chunks (one wave per bucket), in place.
__global__ __launch_bounds__(256) void col_scan_kernel(int* __restrict__ hist, int nchunk,
                                                       int nbkt, int* __restrict__ bcnt) {
    int i = blockIdx.x * 4 + (threadIdx.x >> 6);
    if (i >= nbkt) return;
    int lane = threadIdx.x & 63;
    int run = 0;
    for (int c0 = 0; c0 < nchunk; c0 += 64) {
        int c = c0 + lane;
        int v = (c < nchunk) ? hist[(size_t)c * nbkt + i] : 0;
        int inc = v;
#pragma unroll
        for (int m = 1; m < 64; m <<= 1) {
            int u = __shfl_up(inc, m);
            if (lane >= m) inc += u;
        }
        if (c < nchunk) hist[(size_t)c * nbkt + i] = run + inc - v;
        run += __shfl(inc, 63);
    }
    if (lane == 0) bcnt[i] = run;
}

// K2b: single-block exclusive scan of bcnt -> bbase[0..nbkt]; rowp[n] = E
__global__ __launch_bounds__(256) void bucket_scan_kernel(const int* __restrict__ bcnt, int nbkt,
                                                          int* __restrict__ bbase,
                                                          int* __restrict__ rowp, int n) {
    __shared__ int wsum[4];
    int tid = threadIdx.x, lane = tid & 63, w = tid >> 6;
    int chunk = (nbkt + 255) / 256;
    int begin = tid * chunk;
    int end = begin + chunk; if (end > nbkt) end = nbkt;
    int s = 0;
    for (int i = begin; i < end; ++i) s += bcnt[i];
    int inc = s;
#pragma unroll
    for (int m = 1; m < 64; m <<= 1) {
        int u = __shfl_up(inc, m);
        if (lane >= m) inc += u;
    }
    if (lane == 63) wsum[w] = inc;
    __syncthreads();
    int off = 0;
    for (int i = 0; i < w; ++i) off += wsum[i];
    int run = off + inc - s;
    for (int i = begin; i < end; ++i) {
        bbase[i] = run;
        run += bcnt[i];
    }
    if (tid == 255) { bbase[nbkt] = run; rowp[n] = run; }   // run == E
}

// K3: per-chunk LDS bucket sort. Counts are DERIVED from hist (no recount pass):
// count[b][i] = (b+1<nchunk ? hist[b+1][i] : bcnt[i]) - hist[b][i].
__global__ __launch_bounds__(256) void pair_blocksort_kernel(const int* __restrict__ src,
                                                             const int* __restrict__ dst,
                                                             int E, int nbkt, int nchunk,
                                                             const int* __restrict__ hist,
                                                             const int* __restrict__ bcnt,
                                                             const int* __restrict__ bbase,
                                                             int* __restrict__ part) {
    __shared__ int2 pairs[PS_CHUNK];          // 32 KB
    __shared__ int lbase[MAX_BKT];
    __shared__ int lcur[MAX_BKT];
    __shared__ int gpos[MAX_BKT];
    __shared__ int wsum[4];
    const int tid = threadIdx.x;
    const int b = blockIdx.x;
    const int e0 = b * PS_CHUNK;
    int e1 = e0 + PS_CHUNK; if (e1 > E) e1 = E;

    // derive this chunk's per-bucket counts + global positions from hist
    for (int i = tid; i < nbkt; i += 256) {
        int off0 = hist[(size_t)b * nbkt + i];
        int off1 = (b + 1 < nchunk) ? hist[(size_t)(b + 1) * nbkt + i] : bcnt[i];
        gpos[i] = bbase[i] + off0;
        lcur[i] = off1 - off0;                 // temporarily holds the count
    }
    __syncthreads();
    // scan counters: 256 threads x 4 buckets -> lbase/lcur (local offsets)
    {
        int b0 = tid * 4;
        int v[4]; int s = 0;
#pragma unroll
        for (int k = 0; k < 4; ++k) {
            int bb = b0 + k;
            v[k] = (bb < nbkt) ? lcur[bb] : 0;
            s += v[k];
        }
        int lane = tid & 63, w = tid >> 6;
        int inc = s;
#pragma unroll
        for (int m = 1; m < 64; m <<= 1) {
            int u = __shfl_up(inc, m);
            if (lane >= m) inc += u;
        }
        if (lane == 63) wsum[w] = inc;
        __syncthreads();
        int off = 0;
        for (int i = 0; i < w; ++i) off += wsum[i];
        int run = off + inc - s;
        __syncthreads();
#pragma unroll
        for (int k = 0; k < 4; ++k) {
            int bb = b0 + k;
            if (bb < nbkt) { lbase[bb] = run; lcur[bb] = run; }
            run += v[k];
        }
    }
    __syncthreads();
    // scatter into bucket-sorted LDS order
    for (int i = e0 + tid; i < e1; i += 256) {
        int s = src[i], d = dst[i];
        int p = atomicAdd(&lcur[d >> NPB_SHIFT], 1);
        pairs[p] = make_int2(s, d);
    }
    __syncthreads();
    // write out: consecutive LDS slots in a bucket -> consecutive global slots
    const int cnt = e1 - e0;
    for (int i = tid; i < cnt; i += 256) {
        int2 pr = pairs[i];
        int bk = pr.y >> NPB_SHIFT;
        part[gpos[bk] + (i - lbase[bk])] = (pr.x << NPB_SHIFT) | (pr.y & (NPB - 1));
    }
}

// ---------------- fp16 helpers ----------------

template <bool HALF>
__device__ __forceinline__ float4 ldrow4(const void* H, size_t off) {
    if constexpr (HALF) {
        half4 h = *reinterpret_cast<const half4*>(reinterpret_cast<const _Float16*>(H) + off);
        return make_float4((float)h.x, (float)h.y, (float)h.z, (float)h.w);
    } else {
        return *reinterpret_cast<const float4*>(reinterpret_cast<const float*>(H) + off);
    }
}

template <bool HALF>
__device__ __forceinline__ void strow4(void* H, size_t off, float4 o) {
    if constexpr (HALF) {
        half4 hv;
        hv.x = (_Float16)o.x; hv.y = (_Float16)o.y;
        hv.z = (_Float16)o.z; hv.w = (_Float16)o.w;
        *reinterpret_cast<half4*>(reinterpret_cast<_Float16*>(H) + off) = hv;
    } else {
        *reinterpret_cast<float4*>(reinterpret_cast<float*>(H) + off) = o;
    }
}

// K4: fused bucket_csr + GEMM1.
// Phase 1: build rowp/dinv/csr for this bucket's 64 nodes (dinv kept in LDS).
// Phase 2: H1[r][c] = (X[r][:] · We1[:][c]) * dinv[r], fp16 out (rows = same bucket).
__global__ __launch_bounds__(256) void csr_g1_kernel(
        const int* __restrict__ part, const int* __restrict__ bbase, int n,
        int* __restrict__ rowp, float* __restrict__ dinv, int* __restrict__ csr,
        const float* __restrict__ X, const float* __restrict__ We1,
        void* __restrict__ H1) {
    __shared__ int lcnt[NPB];
    __shared__ float sdinv[NPB];
    __shared__ __align__(16) char smem[50176];   // At[64][68]f (17408B) + Bl[128][64]f (32768B)
    const int b = blockIdx.x, tid = threadIdx.x;
    const int node0 = b << NPB_SHIFT;
    int nloc = n - node0; if (nloc > NPB) nloc = NPB;
    const int p0 = bbase[b], p1 = bbase[b + 1];

    if (tid < NPB) lcnt[tid] = 0;
    __syncthreads();
    for (int i = p0 + tid; i < p1; i += 256)
        atomicAdd(&lcnt[part[i] & (NPB - 1)], 1);
    __syncthreads();
    if (tid < 64) {
        int c = lcnt[tid];
        int inc = c;
#pragma unroll
        for (int m = 1; m < 64; m <<= 1) {
            int u = __shfl_up(inc, m);
            if (tid >= m) inc += u;
        }
        int base = p0 + inc - c;
        float dv = rsqrtf((float)(c + 1));        // +1 self-loop
        if (tid < nloc) {
            rowp[node0 + tid] = base;
            dinv[node0 + tid] = dv;
        }
        sdinv[tid] = dv;
        lcnt[tid] = base;                          // scatter cursor
    }
    __syncthreads();
    for (int i = p0 + tid; i < p1; i += 256) {
        int w = part[i];
        int pos = atomicAdd(&lcnt[w & (NPB - 1)], 1);
        csr[pos] = w >> NPB_SHIFT;                 // src
    }
    __syncthreads();

    // ---- phase 2: 64x64 GEMM tile, K=128 (two 64-chunks) ----
    float (*At)[68] = reinterpret_cast<float (*)[68]>(smem);
    float (*Bl)[64] = reinterpret_cast<float (*)[64]>(smem + 17408);
    const int tx = tid % 16, ty = tid / 16;

    for (int i = tid; i < 128 * 16; i += 256) {    // B panel float4s
        int k = i / 16, c4 = (i % 16) * 4;
        *reinterpret_cast<float4*>(&Bl[k][c4]) =
            *reinterpret_cast<const float4*>(&We1[(size_t)k * 64 + c4]);
    }

    float acc[4][4] = {};
#pragma unroll
    for (int ch = 0; ch < 2; ++ch) {
        if (ch) __syncthreads();
        for (int i = tid; i < 64 * 16; i += 256) {
            int r = i / 16, k0 = (i % 16) * 4;
            int rg = node0 + r; if (rg > n - 1) rg = n - 1;
            float4 xv = *reinterpret_cast<const float4*>(&X[(size_t)rg * 128 + ch * 64 + k0]);
            At[k0 + 0][r] = xv.x;
            At[k0 + 1][r] = xv.y;
            At[k0 + 2][r] = xv.z;
            At[k0 + 3][r] = xv.w;
        }
        __syncthreads();
#pragma unroll 8
        for (int k = 0; k < 64; ++k) {
            float4 a = *reinterpret_cast<const float4*>(&At[k][ty * 4]);
            float4 bb = *reinterpret_cast<const float4*>(&Bl[ch * 64 + k][tx * 4]);
            acc[0][0] = fmaf(a.x, bb.x, acc[0][0]); acc[0][1] = fmaf(a.x, bb.y, acc[0][1]);
            acc[0][2] = fmaf(a.x, bb.z, acc[0][2]); acc[0][3] = fmaf(a.x, bb.w, acc[0][3]);
            acc[1][0] = fmaf(a.y, bb.x, acc[1][0]); acc[1][1] = fmaf(a.y, bb.y, acc[1][1]);
            acc[1][2] = fmaf(a.y, bb.z, acc[1][2]); acc[1][3] = fmaf(a.y, bb.w, acc[1][3]);
            acc[2][0] = fmaf(a.z, bb.x, acc[2][0]); acc[2][1] = fmaf(a.z, bb.y, acc[2][1]);
            acc[2][2] = fmaf(a.z, bb.z, acc[2][2]); acc[2][3] = fmaf(a.z, bb.w, acc[2][3]);
            acc[3][0] = fmaf(a.w, bb.x, acc[3][0]); acc[3][1] = fmaf(a.w, bb.y, acc[3][1]);
            acc[3][2] = fmaf(a.w, bb.z, acc[3][2]); acc[3][3] = fmaf(a.w, bb.w, acc[3][3]);
        }
    }
#pragma unroll
    for (int i = 0; i < 4; ++i) {
        int r = ty * 4 + i;
        int nd = node0 + r;
        if (nd < n) {
            float dv = sdinv[r];
            float4 o = make_float4(acc[i][0] * dv, acc[i][1] * dv,
                                   acc[i][2] * dv, acc[i][3] * dv);
            strow4<true>(H1, (size_t)nd * 64 + tx * 4, o);
        }
    }
}

// K5: block-tiled GEMM: H[r][c] = epi(sum_k X[r][k] W[k][c])
// epi: +bias (BIAS), relu (RELU), * dinv[r] (SCALE); in/out fp32 or fp16.
template <int K, int OUT, int BN, bool BIAS, bool RELU, bool SCALE, bool HALF_IN, bool HALF_OUT>
__global__ __launch_bounds__(16 * (BN / 4)) void gemm_tile_kernel(
        const void* __restrict__ X, const float* __restrict__ W,
        const float* __restrict__ bias, const float* __restrict__ dinv,
        void* __restrict__ Hout, int n) {
    constexpr int BM = 64;
    constexpr int KB = (K > 64) ? 64 : K;
    constexpr int NTHR = 16 * (BN / 4);
    constexpr int KV = KB / 4;

    __shared__ float At[KB][BM + 4];        // [k][r], stride 68 floats
    __shared__ float Bl[K][BN];

    const int tid = threadIdx.x;
    const int tx = tid % (BN / 4);
    const int ty = tid / (BN / 4);
    const int rb = blockIdx.x * BM;
    const int co = blockIdx.y * BN;

    for (int i = tid; i < K * BN / 4; i += NTHR) {
        int k = i / (BN / 4);
        int c0 = (i % (BN / 4)) * 4;
        *reinterpret_cast<float4*>(&Bl[k][c0]) =
            *reinterpret_cast<const float4*>(&W[(size_t)k * OUT + co + c0]);
    }

    float acc[4][4] = {};

#pragma unroll
    for (int ch = 0; ch < K / KB; ++ch) {
        if (ch) __syncthreads();
        for (int i = tid; i < BM * KV; i += NTHR) {
            int r = i / KV;
            int k0 = (i % KV) * 4;
            int rg = rb + r; if (rg > n - 1) rg = n - 1;
            float4 xv = ldrow4<HALF_IN>(X, (size_t)rg * K + ch * KB + k0);
            At[k0 + 0][r] = xv.x;
            At[k0 + 1][r] = xv.y;
            At[k0 + 2][r] = xv.z;
            At[k0 + 3][r] = xv.w;
        }
        __syncthreads();

#pragma unroll 8
        for (int k = 0; k < KB; ++k) {
            float4 a = *reinterpret_cast<const float4*>(&At[k][ty * 4]);
            float4 b = *reinterpret_cast<const float4*>(&Bl[ch * KB + k][tx * 4]);
            acc[0][0] = fmaf(a.x, b.x, acc[0][0]); acc[0][1] = fmaf(a.x, b.y, acc[0][1]);
            acc[0][2] = fmaf(a.x, b.z, acc[0][2]); acc[0][3] = fmaf(a.x, b.w, acc[0][3]);
            acc[1][0] = fmaf(a.y, b.x, acc[1][0]); acc[1][1] = fmaf(a.y, b.y, acc[1][1]);
            acc[1][2] = fmaf(a.y, b.z, acc[1][2]); acc[1][3] = fmaf(a.y, b.w, acc[1][3]);
            acc[2][0] = fmaf(a.z, b.x, acc[2][0]); acc[2][1] = fmaf(a.z, b.y, acc[2][1]);
            acc[2][2] = fmaf(a.z, b.z, acc[2][2]); acc[2][3] = fmaf(a.z, b.w, acc[2][3]);
            acc[3][0] = fmaf(a.w, b.x, acc[3][0]); acc[3][1] = fmaf(a.w, b.y, acc[3][1]);
            acc[3][2] = fmaf(a.w, b.z, acc[3][2]); acc[3][3] = fmaf(a.w, b.w, acc[3][3]);
        }
    }

    float4 bv = make_float4(0.f, 0.f, 0.f, 0.f);
    if (BIAS) bv = *reinterpret_cast<const float4*>(&bias[co + tx * 4]);
    int r0 = rb + ty * 4;
#pragma unroll
    for (int i = 0; i < 4; ++i) {
        int r = r0 + i;
        if (r < n) {
            float4 o;
            o.x = acc[i][0]; o.y = acc[i][1]; o.z = acc[i][2]; o.w = acc[i][3];
            if (BIAS) { o.x += bv.x; o.y += bv.y; o.z += bv.z; o.w += bv.w; }
            if (RELU) {
                o.x = fmaxf(o.x, 0.f); o.y = fmaxf(o.y, 0.f);
                o.z = fmaxf(o.z, 0.f); o.w = fmaxf(o.w, 0.f);
            }
            if (SCALE) {
                float dv = dinv[r];
                o.x *= dv; o.y *= dv; o.z *= dv; o.w *= dv;
            }
            strow4<HALF_OUT>(Hout, (size_t)r * OUT + co + tx * 4, o);
        }
    }
}

// K6: C=32 aggregate, fp16, half8 loads, pipelined csr prefetch (unchanged).
template <int C, bool RELU, bool HAS_BIAS, bool POST_SCALE>
__global__ __launch_bounds__(256) void aggregate_kernel(const _Float16* __restrict__ H,
                                                        const int* __restrict__ row,
                                                        const int* __restrict__ csr_src,
                                                        const float* __restrict__ dinv,
                                                        const float* __restrict__ bias,
                                                        _Float16* __restrict__ Y, int n,
                                                        int E) {
    constexpr int LPN = C / 8;        // lanes covering one row
    constexpr int EG = 64 / LPN;      // edge groups
    int wid = (blockIdx.x * blockDim.x + threadIdx.x) >> 6;
    if (wid >= n) return;             // wave-uniform exit
    int lane = threadIdx.x & 63;
    int g = lane / LPN;
    int c0 = (lane % LPN) * 8;
    const int node = wid;

    float accA[8] = {};
    float accB[8] = {};
    if (g == 0) {
        half8 h = *reinterpret_cast<const half8*>(H + (size_t)node * C + c0);  // self-loop
#pragma unroll
        for (int j = 0; j < 8; ++j) accA[j] = (float)h[j];
    }
    int e = row[node] + g;
    const int end = row[node + 1];
    const int emax = E - 1;
    int idx0 = csr_src[e < emax ? e : emax];
    int idx1 = csr_src[(e + EG) < emax ? (e + EG) : emax];
    for (; e + EG < end; ) {
        int en = e + 2 * EG;
        int nxt0 = csr_src[en < emax ? en : emax];
        int nxt1 = csr_src[(en + EG) < emax ? (en + EG) : emax];
        half8 h0 = *reinterpret_cast<const half8*>(H + (size_t)idx0 * C + c0);
        half8 h1 = *reinterpret_cast<const half8*>(H + (size_t)idx1 * C + c0);
#pragma unroll
        for (int j = 0; j < 8; ++j) { accA[j] += (float)h0[j]; accB[j] += (float)h1[j]; }
        idx0 = nxt0; idx1 = nxt1; e = en;
    }
    if (e < end) {
        half8 h = *reinterpret_cast<const half8*>(H + (size_t)idx0 * C + c0);
#pragma unroll
        for (int j = 0; j < 8; ++j) accA[j] += (float)h[j];
    }
#pragma unroll
    for (int j = 0; j < 8; ++j) accA[j] += accB[j];
#pragma unroll
    for (int m = LPN; m < 64; m <<= 1) {
#pragma unroll
        for (int j = 0; j < 8; ++j) accA[j] += __shfl_xor(accA[j], m);
    }
    if (g == 0) {
        float dv = dinv[node];
        half8 o;
#pragma unroll
        for (int j = 0; j < 8; ++j) {
            float v = accA[j] * dv;
            if (HAS_BIAS) v += bias[c0 + j];
            if (RELU) v = fmaxf(v, 0.f);
            if (POST_SCALE) v *= dv;
            o[j] = (_Float16)v;
        }
        *reinterpret_cast<half8*>(Y + (size_t)node * C + c0) = o;
    }
}

// K6w: C=64 aggregate, WIDE lanes: 4 lanes/row x 16 channels/lane (2x half8),
// EG=16 edge groups -> 2x edge concurrency per wave vs LPN=8. Same request
// count (8 per row), same csr stream (4 lanes/group broadcast the index),
// pipelined csr prefetch. o = dinv*(self+sum) (+bias, relu).
template <bool RELU, bool HAS_BIAS>
__global__ __launch_bounds__(256) void aggregate64w_kernel(const _Float16* __restrict__ H,
                                                           const int* __restrict__ row,
                                                           const int* __restrict__ csr_src,
                                                           const float* __restrict__ dinv,
                                                           const float* __restrict__ bias,
                                                           _Float16* __restrict__ Y, int n,
                                                           int E) {
    constexpr int C = 64;
    constexpr int LPN = 4;            // lanes covering one row
    constexpr int EG = 16;            // edge groups in flight
    int wid = (blockIdx.x * blockDim.x + threadIdx.x) >> 6;
    if (wid >= n) return;             // wave-uniform exit
    int lane = threadIdx.x & 63;
    int g = lane >> 2;                // lane / LPN
    int c0 = (lane & 3) * 16;         // 16 channels per lane
    const int node = wid;

    float accA[16] = {};
    float accB[16] = {};
    if (g == 0) {
        const _Float16* rp = H + (size_t)node * C + c0;
        half8 a = *reinterpret_cast<const half8*>(rp);
        half8 b = *reinterpret_cast<const half8*>(rp + 8);
#pragma unroll
        for (int j = 0; j < 8; ++j) { accA[j] = (float)a[j]; accA[j + 8] = (float)b[j]; }
    }
    int e = row[node] + g;
    const int end = row[node + 1];
    const int emax = E - 1;
    int idx0 = csr_src[e < emax ? e : emax];
    int idx1 = csr_src[(e + EG) < emax ? (e + EG) : emax];
    for (; e + EG < end; ) {
        int en = e + 2 * EG;
        int nxt0 = csr_src[en < emax ? en : emax];
        int nxt1 = csr_src[(en + EG) < emax ? (en + EG) : emax];
        const _Float16* r0 = H + (size_t)idx0 * C + c0;
        const _Float16* r1 = H + (size_t)idx1 * C + c0;
        half8 h0a = *reinterpret_cast<const half8*>(r0);
        half8 h0b = *reinterpret_cast<const half8*>(r0 + 8);
        half8 h1a = *reinterpret_cast<const half8*>(r1);
        half8 h1b = *reinterpret_cast<const half8*>(r1 + 8);
#pragma unroll
        for (int j = 0; j < 8; ++j) {
            accA[j]     += (float)h0a[j];
            accA[j + 8] += (float)h0b[j];
            accB[j]     += (float)h1a[j];
            accB[j + 8] += (float)h1b[j];
        }
        idx0 = nxt0; idx1 = nxt1; e = en;
    }
    if (e < end) {
        const _Float16* r0 = H + (size_t)idx0 * C + c0;
        half8 a = *reinterpret_cast<const half8*>(r0);
        half8 b = *reinterpret_cast<const half8*>(r0 + 8);
#pragma unroll
        for (int j = 0; j < 8; ++j) { accA[j] += (float)a[j]; accA[j + 8] += (float)b[j]; }
    }
#pragma unroll
    for (int j = 0; j < 16; ++j) accA[j] += accB[j];
#pragma unroll
    for (int m = LPN; m < 64; m <<= 1) {
#pragma unroll
        for (int j = 0; j < 16; ++j) accA[j] += __shfl_xor(accA[j], m);
    }
    if (g == 0) {
        float dv = dinv[node];
        half8 o0, o1;
#pragma unroll
        for (int j = 0; j < 8; ++j) {
            float v0 = accA[j] * dv;
            float v1 = accA[j + 8] * dv;
            if (HAS_BIAS) { v0 += bias[c0 + j]; v1 += bias[c0 + 8 + j]; }
            if (RELU) { v0 = fmaxf(v0, 0.f); v1 = fmaxf(v1, 0.f); }
            o0[j] = (_Float16)v0;
            o1[j] = (_Float16)v1;
        }
        _Float16* yp = Y + (size_t)node * C + c0;
        *reinterpret_cast<half8*>(yp) = o0;
        *reinterpret_cast<half8*>(yp + 8) = o1;
    }
}

// ---------------- host launch ----------------

static inline int cdiv(int a, int b) { return (a + b - 1) / b; }

extern "C" void kernel_launch(void* const* d_in, const int* in_sizes, int n_in,
                              void* d_out, int out_size, void* d_ws, size_t ws_size,
                              hipStream_t stream) {
    const float* x   = (const float*)d_in[0];
    const int*   ei  = (const int*)d_in[1];
    const float* We1 = (const float*)d_in[2];
    const float* be1 = (const float*)d_in[3];
    const float* We2 = (const float*)d_in[4];
    const float* be2 = (const float*)d_in[5];
    const float* Wd1 = (const float*)d_in[6];
    const float* bd1 = (const float*)d_in[7];
    const float* Wd2 = (const float*)d_in[8];
    const float* bd2 = (const float*)d_in[9];

    const int n = in_sizes[0] / 128;
    const int E = in_sizes[1] / 2;
    const int* src = ei;
    const int* dst = ei + E;
    const int nbkt = cdiv(n, NPB);
    const int nchunk = cdiv(E, PS_CHUNK);
    const int nrb = cdiv(n, 64);
    const int nwv = cdiv(n * 64, 256);      // one wave per node

    // carve workspace (256B aligned)
    char* ws = (char*)d_ws;
    auto carve = [&](size_t bytes) -> void* {
        void* p = (void*)ws;
        ws += (bytes + 255) & ~(size_t)255;
        return p;
    };
    int*   hist = (int*)carve((size_t)nchunk * nbkt * 4);
    int*   bcnt = (int*)carve((size_t)nbkt * 4);
    int*   bbase= (int*)carve((size_t)(nbkt + 1) * 4);
    int*   part = (int*)carve((size_t)E * 4);
    int*   rowp = (int*)carve((size_t)(n + 1) * 4);
    float* dinv = (float*)carve((size_t)n * 4);
    int*   csr  = (int*)carve((size_t)E * 4);
    _Float16* P1 = (_Float16*)carve((size_t)n * 64 * 2);   // H1s, later Ds
    _Float16* P2 = (_Float16*)carve((size_t)n * 64 * 2);   // B1,  later A4
    _Float16* P3 = (_Float16*)carve((size_t)n * 32 * 2);   // H2s, later A3
    _Float16* P4 = (_Float16*)carve((size_t)n * 32 * 2);   // Zs

    // ---- graph preprocessing ----
    hist_kernel<<<nchunk, 256, 0, stream>>>(dst, E, nbkt, hist);
    col_scan_kernel<<<cdiv(nbkt, 4), 256, 0, stream>>>(hist, nchunk, nbkt, bcnt);
    bucket_scan_kernel<<<1, 256, 0, stream>>>(bcnt, nbkt, bbase, rowp, n);
    pair_blocksort_kernel<<<nchunk, 256, 0, stream>>>(src, dst, E, nbkt, nchunk,
                                                      hist, bcnt, bbase, part);

    // ---- CSR build + layer-1 GEMM fused: H1s = dinv ⊙ (X We1)  [fp16] ----
    csr_g1_kernel<<<nbkt, 256, 0, stream>>>(part, bbase, n, rowp, dinv, csr, x, We1, P1);

    // ---- A1: B1 = relu(dinv⊙agg(H1s)+b1)  [fp16, wide lanes] ----
    aggregate64w_kernel<true, true>
        <<<nwv, 256, 0, stream>>>(P1, rowp, csr, dinv, be1, P2, n, E);

    // ---- G2: H2s = (B1 We2)⊙dinv  [fp16] ----
    gemm_tile_kernel<64, 32, 32, false, false, true, true, true>
        <<<dim3(nrb, 1), 128, 0, stream>>>(P2, We2, nullptr, dinv, P3, n);

    // ---- A2: Zs = dinv⊙(dinv⊙agg(H2s)+b2)  [fp16] ----
    aggregate_kernel<32, false, true, true>
        <<<nwv, 256, 0, stream>>>(P3, rowp, csr, dinv, be2, P4, n, E);

    // ---- A3: A3 = dinv⊙agg(Zs)  [fp16] ----
    aggregate_kernel<32, false, false, false>
        <<<nwv, 256, 0, stream>>>(P4, rowp, csr, dinv, nullptr, P3, n, E);

    // ---- G3: Ds = dinv⊙relu(A3 Wd1 + b3)  [fp16] ----
    gemm_tile_kernel<32, 64, 64, true, true, true, true, true>
        <<<dim3(nrb, 1), 256, 0, stream>>>(P3, Wd1, bd1, dinv, P1, n);

    // ---- A4: A4 = dinv⊙agg(Ds)  [fp16, wide lanes] ----
    aggregate64w_kernel<false, false>
        <<<nwv, 256, 0, stream>>>(P1, rowp, csr, dinv, nullptr, P2, n, E);

    // ---- G4: out = A4 Wd2 + b4  [fp32] ----
    gemm_tile_kernel<64, 128, 64, true, false, false, true, false>
        <<<dim3(nrb, 2), 256, 0, stream>>>(P2, Wd2, bd2, dinv, d_out, n);
}

// Round 17
// 177.744 us; speedup vs baseline: 1.1444x; 1.1444x over previous
//
#include <hip/hip_runtime.h>

typedef _Float16 half4 __attribute__((ext_vector_type(4)));
typedef _Float16 half8 __attribute__((ext_vector_type(8)));

// ---------------- graph preprocessing (deterministic bucketed sort) ----------------
// Buckets of 64 consecutive dst nodes; chunks of 4096 edges.
// hist[chunk][bucket] -> per-bucket scan across chunks -> deterministic scatter.
// part[] entries packed as (src << 6) | (dst & 63).

static constexpr int NPB_SHIFT = 6;           // 64 nodes per bucket
static constexpr int NPB = 1 << NPB_SHIFT;
static constexpr int MAX_BKT = 1024;          // supports n <= 65536 (src<<6 fits int)
static constexpr int PS_CHUNK = 4096;         // edges per chunk

// K1: per-chunk bucket histogram (LDS atomics only)
__global__ __launch_bounds__(256) void hist_kernel(const int* __restrict__ dst, int E,
                                                   int nbkt, int* __restrict__ hist) {
    __shared__ int lc[MAX_BKT];
    int tid = threadIdx.x;
    int b = blockIdx.x;
    int e0 = b * PS_CHUNK;
    int e1 = e0 + PS_CHUNK; if (e1 > E) e1 = E;
    for (int i = tid; i < nbkt; i += 256) lc[i] = 0;
    __syncthreads();
    for (int i = e0 + tid; i < e1; i += 256)
        atomicAdd(&lc[dst[i] >> NPB_SHIFT], 1);
    __syncthreads();
    for (int i = tid; i < nbkt; i += 256) hist[(size_t)b * nbkt + i] = lc[i];
}

// K2a: per-bucket exclusive scan across chunks (one wave per bucket), in place.
__global__ __launch_bounds__(256) void col_scan_kernel(int* __restrict__ hist, int nchunk,
                                                       int nbkt, int* __restrict__ bcnt) {
    int i = blockIdx.x * 4 + (threadIdx.x >> 6);
    if (i >= nbkt) return;
    int lane = threadIdx.x & 63;
    int run = 0;
    for (int c0 = 0; c0 < nchunk; c0 += 64) {
        int c = c0 + lane;
        int v = (c < nchunk) ? hist[(size_t)c * nbkt + i] : 0;
        int inc = v;
#pragma unroll
        for (int m = 1; m < 64; m <<= 1) {
            int u = __shfl_up(inc, m);
            if (lane >= m) inc += u;
        }
        if (c < nchunk) hist[(size_t)c * nbkt + i] = run + inc - v;
        run += __shfl(inc, 63);
    }
    if (lane == 0) bcnt[i] = run;
}

// K2b: single-block exclusive scan of bcnt -> bbase[0..nbkt]; rowp[n] = E
__global__ __launch_bounds__(256) void bucket_scan_kernel(const int* __restrict__ bcnt, int nbkt,
                                                          int* __restrict__ bbase,
                                                          int* __restrict__ rowp, int n) {
    __shared__ int wsum[4];
    int tid = threadIdx.x, lane = tid & 63, w = tid >> 6;
    int chunk = (nbkt + 255) / 256;
    int begin = tid * chunk;
    int end = begin + chunk; if (end > nbkt) end = nbkt;
    int s = 0;
    for (int i = begin; i < end; ++i) s += bcnt[i];
    int inc = s;
#pragma unroll
    for (int m = 1; m < 64; m <<= 1) {
        int u = __shfl_up(inc, m);
        if (lane >= m) inc += u;
    }
    if (lane == 63) wsum[w] = inc;
    __syncthreads();
    int off = 0;
    for (int i = 0; i < w; ++i) off += wsum[i];
    int run = off + inc - s;
    for (int i = begin; i < end; ++i) {
        bbase[i] = run;
        run += bcnt[i];
    }
    if (tid == 255) { bbase[nbkt] = run; rowp[n] = run; }   // run == E
}

// K3: per-chunk LDS bucket sort. Counts are DERIVED from hist (no recount pass):
// count[b][i] = (b+1<nchunk ? hist[b+1][i] : bcnt[i]) - hist[b][i].
__global__ __launch_bounds__(256) void pair_blocksort_kernel(const int* __restrict__ src,
                                                             const int* __restrict__ dst,
                                                             int E, int nbkt, int nchunk,
                                                             const int* __restrict__ hist,
                                                             const int* __restrict__ bcnt,
                                                             const int* __restrict__ bbase,
                                                             int* __restrict__ part) {
    __shared__ int2 pairs[PS_CHUNK];          // 32 KB
    __shared__ int lbase[MAX_BKT];
    __shared__ int lcur[MAX_BKT];
    __shared__ int gpos[MAX_BKT];
    __shared__ int wsum[4];
    const int tid = threadIdx.x;
    const int b = blockIdx.x;
    const int e0 = b * PS_CHUNK;
    int e1 = e0 + PS_CHUNK; if (e1 > E) e1 = E;

    // derive this chunk's per-bucket counts + global positions from hist
    for (int i = tid; i < nbkt; i += 256) {
        int off0 = hist[(size_t)b * nbkt + i];
        int off1 = (b + 1 < nchunk) ? hist[(size_t)(b + 1) * nbkt + i] : bcnt[i];
        gpos[i] = bbase[i] + off0;
        lcur[i] = off1 - off0;                 // temporarily holds the count
    }
    __syncthreads();
    // scan counters: 256 threads x 4 buckets -> lbase/lcur (local offsets)
    {
        int b0 = tid * 4;
        int v[4]; int s = 0;
#pragma unroll
        for (int k = 0; k < 4; ++k) {
            int bb = b0 + k;
            v[k] = (bb < nbkt) ? lcur[bb] : 0;
            s += v[k];
        }
        int lane = tid & 63, w = tid >> 6;
        int inc = s;
#pragma unroll
        for (int m = 1; m < 64; m <<= 1) {
            int u = __shfl_up(inc, m);
            if (lane >= m) inc += u;
        }
        if (lane == 63) wsum[w] = inc;
        __syncthreads();
        int off = 0;
        for (int i = 0; i < w; ++i) off += wsum[i];
        int run = off + inc - s;
        __syncthreads();
#pragma unroll
        for (int k = 0; k < 4; ++k) {
            int bb = b0 + k;
            if (bb < nbkt) { lbase[bb] = run; lcur[bb] = run; }
            run += v[k];
        }
    }
    __syncthreads();
    // scatter into bucket-sorted LDS order
    for (int i = e0 + tid; i < e1; i += 256) {
        int s = src[i], d = dst[i];
        int p = atomicAdd(&lcur[d >> NPB_SHIFT], 1);
        pairs[p] = make_int2(s, d);
    }
    __syncthreads();
    // write out: consecutive LDS slots in a bucket -> consecutive global slots
    const int cnt = e1 - e0;
    for (int i = tid; i < cnt; i += 256) {
        int2 pr = pairs[i];
        int bk = pr.y >> NPB_SHIFT;
        part[gpos[bk] + (i - lbase[bk])] = (pr.x << NPB_SHIFT) | (pr.y & (NPB - 1));
    }
}

// ---------------- fp16 helpers ----------------

template <bool HALF>
__device__ __forceinline__ float4 ldrow4(const void* H, size_t off) {
    if constexpr (HALF) {
        half4 h = *reinterpret_cast<const half4*>(reinterpret_cast<const _Float16*>(H) + off);
        return make_float4((float)h.x, (float)h.y, (float)h.z, (float)h.w);
    } else {
        return *reinterpret_cast<const float4*>(reinterpret_cast<const float*>(H) + off);
    }
}

template <bool HALF>
__device__ __forceinline__ void strow4(void* H, size_t off, float4 o) {
    if constexpr (HALF) {
        half4 hv;
        hv.x = (_Float16)o.x; hv.y = (_Float16)o.y;
        hv.z = (_Float16)o.z; hv.w = (_Float16)o.w;
        *reinterpret_cast<half4*>(reinterpret_cast<_Float16*>(H) + off) = hv;
    } else {
        *reinterpret_cast<float4*>(reinterpret_cast<float*>(H) + off) = o;
    }
}

// K4: fused bucket_csr + GEMM1.
// Phase 1: build rowp/dinv/csr for this bucket's 64 nodes (dinv kept in LDS).
// Phase 2: H1[r][c] = (X[r][:] · We1[:][c]) * dinv[r], fp16 out (rows = same bucket).
__global__ __launch_bounds__(256) void csr_g1_kernel(
        const int* __restrict__ part, const int* __restrict__ bbase, int n,
        int* __restrict__ rowp, float* __restrict__ dinv, int* __restrict__ csr,
        const float* __restrict__ X, const float* __restrict__ We1,
        void* __restrict__ H1) {
    __shared__ int lcnt[NPB];
    __shared__ float sdinv[NPB];
    __shared__ __align__(16) char smem[50176];   // At[64][68]f (17408B) + Bl[128][64]f (32768B)
    const int b = blockIdx.x, tid = threadIdx.x;
    const int node0 = b << NPB_SHIFT;
    int nloc = n - node0; if (nloc > NPB) nloc = NPB;
    const int p0 = bbase[b], p1 = bbase[b + 1];

    if (tid < NPB) lcnt[tid] = 0;
    __syncthreads();
    for (int i = p0 + tid; i < p1; i += 256)
        atomicAdd(&lcnt[part[i] & (NPB - 1)], 1);
    __syncthreads();
    if (tid < 64) {
        int c = lcnt[tid];
        int inc = c;
#pragma unroll
        for (int m = 1; m < 64; m <<= 1) {
            int u = __shfl_up(inc, m);
            if (tid >= m) inc += u;
        }
        int base = p0 + inc - c;
        float dv = rsqrtf((float)(c + 1));        // +1 self-loop
        if (tid < nloc) {
            rowp[node0 + tid] = base;
            dinv[node0 + tid] = dv;
        }
        sdinv[tid] = dv;
        lcnt[tid] = base;                          // scatter cursor
    }
    __syncthreads();
    for (int i = p0 + tid; i < p1; i += 256) {
        int w = part[i];
        int pos = atomicAdd(&lcnt[w & (NPB - 1)], 1);
        csr[pos] = w >> NPB_SHIFT;                 // src
    }
    __syncthreads();

    // ---- phase 2: 64x64 GEMM tile, K=128 (two 64-chunks) ----
    float (*At)[68] = reinterpret_cast<float (*)[68]>(smem);
    float (*Bl)[64] = reinterpret_cast<float (*)[64]>(smem + 17408);
    const int tx = tid % 16, ty = tid / 16;

    for (int i = tid; i < 128 * 16; i += 256) {    // B panel float4s
        int k = i / 16, c4 = (i % 16) * 4;
        *reinterpret_cast<float4*>(&Bl[k][c4]) =
            *reinterpret_cast<const float4*>(&We1[(size_t)k * 64 + c4]);
    }

    float acc[4][4] = {};
#pragma unroll
    for (int ch = 0; ch < 2; ++ch) {
        if (ch) __syncthreads();
        for (int i = tid; i < 64 * 16; i += 256) {
            int r = i / 16, k0 = (i % 16) * 4;
            int rg = node0 + r; if (rg > n - 1) rg = n - 1;
            float4 xv = *reinterpret_cast<const float4*>(&X[(size_t)rg * 128 + ch * 64 + k0]);
            At[k0 + 0][r] = xv.x;
            At[k0 + 1][r] = xv.y;
            At[k0 + 2][r] = xv.z;
            At[k0 + 3][r] = xv.w;
        }
        __syncthreads();
#pragma unroll 8
        for (int k = 0; k < 64; ++k) {
            float4 a = *reinterpret_cast<const float4*>(&At[k][ty * 4]);
            float4 bb = *reinterpret_cast<const float4*>(&Bl[ch * 64 + k][tx * 4]);
            acc[0][0] = fmaf(a.x, bb.x, acc[0][0]); acc[0][1] = fmaf(a.x, bb.y, acc[0][1]);
            acc[0][2] = fmaf(a.x, bb.z, acc[0][2]); acc[0][3] = fmaf(a.x, bb.w, acc[0][3]);
            acc[1][0] = fmaf(a.y, bb.x, acc[1][0]); acc[1][1] = fmaf(a.y, bb.y, acc[1][1]);
            acc[1][2] = fmaf(a.y, bb.z, acc[1][2]); acc[1][3] = fmaf(a.y, bb.w, acc[1][3]);
            acc[2][0] = fmaf(a.z, bb.x, acc[2][0]); acc[2][1] = fmaf(a.z, bb.y, acc[2][1]);
            acc[2][2] = fmaf(a.z, bb.z, acc[2][2]); acc[2][3] = fmaf(a.z, bb.w, acc[2][3]);
            acc[3][0] = fmaf(a.w, bb.x, acc[3][0]); acc[3][1] = fmaf(a.w, bb.y, acc[3][1]);
            acc[3][2] = fmaf(a.w, bb.z, acc[3][2]); acc[3][3] = fmaf(a.w, bb.w, acc[3][3]);
        }
    }
#pragma unroll
    for (int i = 0; i < 4; ++i) {
        int r = ty * 4 + i;
        int nd = node0 + r;
        if (nd < n) {
            float dv = sdinv[r];
            float4 o = make_float4(acc[i][0] * dv, acc[i][1] * dv,
                                   acc[i][2] * dv, acc[i][3] * dv);
            strow4<true>(H1, (size_t)nd * 64 + tx * 4, o);
        }
    }
}

// K5: block-tiled GEMM: H[r][c] = epi(sum_k X[r][k] W[k][c])
// epi: +bias (BIAS), relu (RELU), * dinv[r] (SCALE); in/out fp32 or fp16.
template <int K, int OUT, int BN, bool BIAS, bool RELU, bool SCALE, bool HALF_IN, bool HALF_OUT>
__global__ __launch_bounds__(16 * (BN / 4)) void gemm_tile_kernel(
        const void* __restrict__ X, const float* __restrict__ W,
        const float* __restrict__ bias, const float* __restrict__ dinv,
        void* __restrict__ Hout, int n) {
    constexpr int BM = 64;
    constexpr int KB = (K > 64) ? 64 : K;
    constexpr int NTHR = 16 * (BN / 4);
    constexpr int KV = KB / 4;

    __shared__ float At[KB][BM + 4];        // [k][r], stride 68 floats
    __shared__ float Bl[K][BN];

    const int tid = threadIdx.x;
    const int tx = tid % (BN / 4);
    const int ty = tid / (BN / 4);
    const int rb = blockIdx.x * BM;
    const int co = blockIdx.y * BN;

    for (int i = tid; i < K * BN / 4; i += NTHR) {
        int k = i / (BN / 4);
        int c0 = (i % (BN / 4)) * 4;
        *reinterpret_cast<float4*>(&Bl[k][c0]) =
            *reinterpret_cast<const float4*>(&W[(size_t)k * OUT + co + c0]);
    }

    float acc[4][4] = {};

#pragma unroll
    for (int ch = 0; ch < K / KB; ++ch) {
        if (ch) __syncthreads();
        for (int i = tid; i < BM * KV; i += NTHR) {
            int r = i / KV;
            int k0 = (i % KV) * 4;
            int rg = rb + r; if (rg > n - 1) rg = n - 1;
            float4 xv = ldrow4<HALF_IN>(X, (size_t)rg * K + ch * KB + k0);
            At[k0 + 0][r] = xv.x;
            At[k0 + 1][r] = xv.y;
            At[k0 + 2][r] = xv.z;
            At[k0 + 3][r] = xv.w;
        }
        __syncthreads();

#pragma unroll 8
        for (int k = 0; k < KB; ++k) {
            float4 a = *reinterpret_cast<const float4*>(&At[k][ty * 4]);
            float4 b = *reinterpret_cast<const float4*>(&Bl[ch * KB + k][tx * 4]);
            acc[0][0] = fmaf(a.x, b.x, acc[0][0]); acc[0][1] = fmaf(a.x, b.y, acc[0][1]);
            acc[0][2] = fmaf(a.x, b.z, acc[0][2]); acc[0][3] = fmaf(a.x, b.w, acc[0][3]);
            acc[1][0] = fmaf(a.y, b.x, acc[1][0]); acc[1][1] = fmaf(a.y, b.y, acc[1][1]);
            acc[1][2] = fmaf(a.y, b.z, acc[1][2]); acc[1][3] = fmaf(a.y, b.w, acc[1][3]);
            acc[2][0] = fmaf(a.z, b.x, acc[2][0]); acc[2][1] = fmaf(a.z, b.y, acc[2][1]);
            acc[2][2] = fmaf(a.z, b.z, acc[2][2]); acc[2][3] = fmaf(a.z, b.w, acc[2][3]);
            acc[3][0] = fmaf(a.w, b.x, acc[3][0]); acc[3][1] = fmaf(a.w, b.y, acc[3][1]);
            acc[3][2] = fmaf(a.w, b.z, acc[3][2]); acc[3][3] = fmaf(a.w, b.w, acc[3][3]);
        }
    }

    float4 bv = make_float4(0.f, 0.f, 0.f, 0.f);
    if (BIAS) bv = *reinterpret_cast<const float4*>(&bias[co + tx * 4]);
    int r0 = rb + ty * 4;
#pragma unroll
    for (int i = 0; i < 4; ++i) {
        int r = r0 + i;
        if (r < n) {
            float4 o;
            o.x = acc[i][0]; o.y = acc[i][1]; o.z = acc[i][2]; o.w = acc[i][3];
            if (BIAS) { o.x += bv.x; o.y += bv.y; o.z += bv.z; o.w += bv.w; }
            if (RELU) {
                o.x = fmaxf(o.x, 0.f); o.y = fmaxf(o.y, 0.f);
                o.z = fmaxf(o.z, 0.f); o.w = fmaxf(o.w, 0.f);
            }
            if (SCALE) {
                float dv = dinv[r];
                o.x *= dv; o.y *= dv; o.z *= dv; o.w *= dv;
            }
            strow4<HALF_OUT>(Hout, (size_t)r * OUT + co + tx * 4, o);
        }
    }
}

// K6: aggregate, fp16 in/out, half8 loads, SOFTWARE-PIPELINED csr prefetch:
// the next pair of edge indices is loaded before the current pair's rows are
// gathered, overlapping csr latency under gather latency (clamped loads keep
// the loop branch-free).
// o = dinv[d]*(H[d]+sum H[s]) (+bias, relu, post-scale).
template <int C, bool RELU, bool HAS_BIAS, bool POST_SCALE>
__global__ __launch_bounds__(256) void aggregate_kernel(const _Float16* __restrict__ H,
                                                        const int* __restrict__ row,
                                                        const int* __restrict__ csr_src,
                                                        const float* __restrict__ dinv,
                                                        const float* __restrict__ bias,
                                                        _Float16* __restrict__ Y, int n,
                                                        int E) {
    constexpr int LPN = C / 8;        // lanes covering one row: 8 (C64) / 4 (C32)
    constexpr int EG = 64 / LPN;      // edge groups: 8 / 16
    int wid = (blockIdx.x * blockDim.x + threadIdx.x) >> 6;
    if (wid >= n) return;             // wave-uniform exit
    int lane = threadIdx.x & 63;
    int g = lane / LPN;
    int c0 = (lane % LPN) * 8;
    const int node = wid;

    float accA[8] = {};
    float accB[8] = {};
    if (g == 0) {
        half8 h = *reinterpret_cast<const half8*>(H + (size_t)node * C + c0);  // self-loop
#pragma unroll
        for (int j = 0; j < 8; ++j) accA[j] = (float)h[j];
    }
    int e = row[node] + g;
    const int end = row[node + 1];
    const int emax = E - 1;
    // prologue: indices for the first pair (clamped, unconditional)
    int idx0 = csr_src[e < emax ? e : emax];
    int idx1 = csr_src[(e + EG) < emax ? (e + EG) : emax];
    for (; e + EG < end; ) {
        int en = e + 2 * EG;
        int nxt0 = csr_src[en < emax ? en : emax];              // prefetch next pair
        int nxt1 = csr_src[(en + EG) < emax ? (en + EG) : emax];
        half8 h0 = *reinterpret_cast<const half8*>(H + (size_t)idx0 * C + c0);
        half8 h1 = *reinterpret_cast<const half8*>(H + (size_t)idx1 * C + c0);
#pragma unroll
        for (int j = 0; j < 8; ++j) { accA[j] += (float)h0[j]; accB[j] += (float)h1[j]; }
        idx0 = nxt0; idx1 = nxt1; e = en;
    }
    if (e < end) {
        half8 h = *reinterpret_cast<const half8*>(H + (size_t)idx0 * C + c0);
#pragma unroll
        for (int j = 0; j < 8; ++j) accA[j] += (float)h[j];
    }
#pragma unroll
    for (int j = 0; j < 8; ++j) accA[j] += accB[j];
#pragma unroll
    for (int m = LPN; m < 64; m <<= 1) {
#pragma unroll
        for (int j = 0; j < 8; ++j) accA[j] += __shfl_xor(accA[j], m);
    }
    if (g == 0) {
        float dv = dinv[node];
        half8 o;
#pragma unroll
        for (int j = 0; j < 8; ++j) {
            float v = accA[j] * dv;
            if (HAS_BIAS) v += bias[c0 + j];
            if (RELU) v = fmaxf(v, 0.f);
            if (POST_SCALE) v *= dv;
            o[j] = (_Float16)v;
        }
        *reinterpret_cast<half8*>(Y + (size_t)node * C + c0) = o;
    }
}

// ---------------- host launch ----------------

static inline int cdiv(int a, int b) { return (a + b - 1) / b; }

extern "C" void kernel_launch(void* const* d_in, const int* in_sizes, int n_in,
                              void* d_out, int out_size, void* d_ws, size_t ws_size,
                              hipStream_t stream) {
    const float* x   = (const float*)d_in[0];
    const int*   ei  = (const int*)d_in[1];
    const float* We1 = (const float*)d_in[2];
    const float* be1 = (const float*)d_in[3];
    const float* We2 = (const float*)d_in[4];
    const float* be2 = (const float*)d_in[5];
    const float* Wd1 = (const float*)d_in[6];
    const float* bd1 = (const float*)d_in[7];
    const float* Wd2 = (const float*)d_in[8];
    const float* bd2 = (const float*)d_in[9];

    const int n = in_sizes[0] / 128;
    const int E = in_sizes[1] / 2;
    const int* src = ei;
    const int* dst = ei + E;
    const int nbkt = cdiv(n, NPB);
    const int nchunk = cdiv(E, PS_CHUNK);
    const int nrb = cdiv(n, 64);
    const int nwv = cdiv(n * 64, 256);      // one wave per node

    // carve workspace (256B aligned)
    char* ws = (char*)d_ws;
    auto carve = [&](size_t bytes) -> void* {
        void* p = (void*)ws;
        ws += (bytes + 255) & ~(size_t)255;
        return p;
    };
    int*   hist = (int*)carve((size_t)nchunk * nbkt * 4);
    int*   bcnt = (int*)carve((size_t)nbkt * 4);
    int*   bbase= (int*)carve((size_t)(nbkt + 1) * 4);
    int*   part = (int*)carve((size_t)E * 4);
    int*   rowp = (int*)carve((size_t)(n + 1) * 4);
    float* dinv = (float*)carve((size_t)n * 4);
    int*   csr  = (int*)carve((size_t)E * 4);
    _Float16* P1 = (_Float16*)carve((size_t)n * 64 * 2);   // H1s, later Ds
    _Float16* P2 = (_Float16*)carve((size_t)n * 64 * 2);   // B1,  later A4
    _Float16* P3 = (_Float16*)carve((size_t)n * 32 * 2);   // H2s, later A3
    _Float16* P4 = (_Float16*)carve((size_t)n * 32 * 2);   // Zs

    // ---- graph preprocessing ----
    hist_kernel<<<nchunk, 256, 0, stream>>>(dst, E, nbkt, hist);
    col_scan_kernel<<<cdiv(nbkt, 4), 256, 0, stream>>>(hist, nchunk, nbkt, bcnt);
    bucket_scan_kernel<<<1, 256, 0, stream>>>(bcnt, nbkt, bbase, rowp, n);
    pair_blocksort_kernel<<<nchunk, 256, 0, stream>>>(src, dst, E, nbkt, nchunk,
                                                      hist, bcnt, bbase, part);

    // ---- CSR build + layer-1 GEMM fused: H1s = dinv ⊙ (X We1)  [fp16] ----
    csr_g1_kernel<<<nbkt, 256, 0, stream>>>(part, bbase, n, rowp, dinv, csr, x, We1, P1);

    // ---- A1: B1 = relu(dinv⊙agg(H1s)+b1)  [fp16] ----
    aggregate_kernel<64, true, true, false>
        <<<nwv, 256, 0, stream>>>(P1, rowp, csr, dinv, be1, P2, n, E);

    // ---- G2: H2s = (B1 We2)⊙dinv  [fp16] ----
    gemm_tile_kernel<64, 32, 32, false, false, true, true, true>
        <<<dim3(nrb, 1), 128, 0, stream>>>(P2, We2, nullptr, dinv, P3, n);

    // ---- A2: Zs = dinv⊙(dinv⊙agg(H2s)+b2)  [fp16] ----
    aggregate_kernel<32, false, true, true>
        <<<nwv, 256, 0, stream>>>(P3, rowp, csr, dinv, be2, P4, n, E);

    // ---- A3: A3 = dinv⊙agg(Zs)  [fp16] ----
    aggregate_kernel<32, false, false, false>
        <<<nwv, 256, 0, stream>>>(P4, rowp, csr, dinv, nullptr, P3, n, E);

    // ---- G3: Ds = dinv⊙relu(A3 Wd1 + b3)  [fp16] ----
    gemm_tile_kernel<32, 64, 64, true, true, true, true, true>
        <<<dim3(nrb, 1), 256, 0, stream>>>(P3, Wd1, bd1, dinv, P1, n);

    // ---- A4: A4 = dinv⊙agg(Ds)  [fp16] ----
    aggregate_kernel<64, false, false, false>
        <<<nwv, 256, 0, stream>>>(P1, rowp, csr, dinv, nullptr, P2, n, E);

    // ---- G4: out = A4 Wd2 + b4  [fp32] ----
    gemm_tile_kernel<64, 128, 64, true, false, false, true, false>
        <<<dim3(nrb, 2), 256, 0, stream>>>(P2, Wd2, bd2, dinv, d_out, n);
}